// Round 6
// baseline (1149.722 us; speedup 1.0000x reference)
//
#include <hip/hip_runtime.h>
#include <hip/hip_bf16.h>

#define E_EDGES 131072
#define NNODES  8192
#define NB      16384   // N_NODES * BATCH rows
#define HID     256
#define EDIM    64
#define MLPH    512
#define OUTD    128
#define NIT     3

typedef short s16x4 __attribute__((ext_vector_type(4)));
typedef short s16x8 __attribute__((ext_vector_type(8)));
typedef float f32x4 __attribute__((ext_vector_type(4)));

__device__ __forceinline__ short f2bf(float f){
  unsigned int x = __builtin_bit_cast(unsigned int, f);
  x += 0x7fffu + ((x >> 16) & 1u);          // RNE
  return (short)(x >> 16);
}
__device__ __forceinline__ float bf2f(short s){
  unsigned int x = ((unsigned int)(unsigned short)s) << 16;
  return __builtin_bit_cast(float, x);
}
__device__ __forceinline__ void gload_lds16(const void* g, void* l){
  __builtin_amdgcn_global_load_lds(
      (const __attribute__((address_space(1))) void*)g,
      (__attribute__((address_space(3))) void*)l, 16, 0, 0);
}
#define MFMA16(a,b,c) __builtin_amdgcn_mfma_f32_16x16x32_bf16((a),(b),(c),0,0,0)

// ===========================================================================
// edge_fused: per block = 16 nodes (32 S-rows). E1 never hits memory:
//   - BtE (pre-swizzled) staged to LDS once (64 KB), reused by ~32 tiles.
//   - per 16-edge-row tile: A gathered per-lane from ebf (16B frags),
//     MFMA K=64 -> raw E1 tile in LDS T [16][512] bf16 (row-swizzled).
//   - accum pass: thread owns (S-row sr=tid>>4, cols (tid&15)*32 .. +31) in
//     f32 regs; for each edge of its node in the tile:
//       acc += relu(T[er] + P1[nd] + P2[src] + b1)   (P terms if USE_P)
//   - end: S[row] = bf16(acc)  (deg-0 nodes -> 0, matching segment_sum)
// ===========================================================================
template<bool USE_P>
__global__ __launch_bounds__(512, 4)
void edge_fused(const short* __restrict__ ebf, const short* __restrict__ BtE,
                const short* __restrict__ P, const int* __restrict__ ceid,
                const int* __restrict__ csrc, const int* __restrict__ rs,
                const float* __restrict__ b1, short* __restrict__ S)
{
  __shared__ __align__(16) short Bl[512 * 64];   // 64 KB (swizzled layout)
  __shared__ __align__(16) short T[16 * 512];    // 16 KB (row-swizzled)

  const int tid = threadIdx.x;
  const int w = tid >> 6, l = tid & 63;
  const int lr = l & 15, lg = l >> 4;
  const int node0 = blockIdx.x * 16;
  const int p0 = rs[node0], p1 = rs[node0 + 16];

  // stage BtE -> Bl (global already swizzled; linear LDS dest)
#pragma unroll
  for (int i = 0; i < 8; ++i)
    gload_lds16((const char*)BtE + i * 8192 + w * 1024 + l * 16,
                (char*)Bl + i * 8192 + w * 1024);

  // accum ownership
  const int sr = tid >> 4;                 // 0..31 S-row within block
  const int nd = node0 + (sr >> 1);
  const int sb = sr & 1;
  const int c0 = (tid & 15) * 32;
  const int ps = rs[nd], pe = rs[nd + 1];

  float acc[32], p1c[32];
#pragma unroll
  for (int c = 0; c < 32; ++c) acc[c] = 0.f;
#pragma unroll
  for (int c = 0; c < 32; ++c) p1c[c] = b1[c0 + c];
  if (USE_P){
#pragma unroll
    for (int u = 0; u < 4; ++u){
      s16x8 pv = *(const s16x8*)(P + (size_t)(nd * 2 + sb) * 1024 + c0 + u * 8);
#pragma unroll
      for (int j = 0; j < 8; ++j) p1c[u * 8 + j] += bf2f(pv[j]);
    }
  }

  const int nt = (2 * (p1 - p0) + 15) >> 4;   // 16-row tiles (8 edges each)

  // prefetch tile 0 A-frags: lane row lr -> edge p0 + (lr>>1), batch lr&1
  s16x8 a0 = {}, a1 = {};
  if (nt > 0){
    int pl = p0 + (lr >> 1); if (pl > p1 - 1) pl = p1 - 1;
    int eid = ceid[pl];
    const short* ap = ebf + ((size_t)eid * 2 + (lr & 1)) * 64 + lg * 8;
    a0 = *(const s16x8*)ap;
    a1 = *(const s16x8*)(ap + 32);
  }
  __syncthreads();                           // Bl staged

  for (int t = 0; t < nt; ++t){
    // prefetch next tile's eid early (hides L2 latency under MFMA)
    int pl_n = p0 + (t + 1) * 8 + (lr >> 1); if (pl_n > p1 - 1) pl_n = p1 - 1;
    int eid_n = ceid[pl_n];

    // MFMA: 1 m-frag x 4 n-frags x K=64 ; wave covers cols w*64..+63
    f32x4 cf[4];
#pragma unroll
    for (int n = 0; n < 4; ++n) cf[n] = (f32x4){0.f,0.f,0.f,0.f};
#pragma unroll
    for (int n = 0; n < 4; ++n){
      int brow = w * 64 + n * 16 + lr;
      const short* bp = Bl + brow * 64;
      s16x8 b0v = *(const s16x8*)(bp + ((lg * 8)      ^ ((brow & 7) << 3)));
      s16x8 b1v = *(const s16x8*)(bp + ((32 + lg * 8) ^ ((brow & 7) << 3)));
      cf[n] = MFMA16(a0, b0v, cf[n]);
      cf[n] = MFMA16(a1, b1v, cf[n]);
    }
    // issue next-tile A gather (lands during accum phase)
    {
      const short* apn = ebf + ((size_t)eid_n * 2 + (lr & 1)) * 64 + lg * 8;
      a0 = *(const s16x8*)apn;
      a1 = *(const s16x8*)(apn + 32);
    }
    // write raw E1 frag to T (bf16, row-swizzled)
#pragma unroll
    for (int n = 0; n < 4; ++n){
      int c = w * 64 + n * 16 + lr;
#pragma unroll
      for (int r = 0; r < 4; ++r){
        int row = lg * 4 + r;
        T[row * 512 + (c ^ ((row & 7) << 3))] = f2bf(cf[n][r]);
      }
    }
    __syncthreads();                         // T visible

    // accum: edges of this tile belonging to (nd, sb)
    int pt0 = p0 + t * 8;
    int qa = ps > pt0 ? ps : pt0;
    int qb = pt0 + 8 < p1 ? pt0 + 8 : p1;
    if (pe < qb) qb = pe;
    for (int p = qa; p < qb; ++p){
      int er = 2 * (p - pt0) + sb;
      int rx = (er & 7) << 3;
      const short* trow = T + er * 512;
      if (USE_P){
        const short* p2r = P + (size_t)(csrc[p] * 2 + sb) * 1024 + 512 + c0;
#pragma unroll
        for (int u = 0; u < 4; ++u){
          s16x8 tv = *(const s16x8*)(trow + ((c0 + u * 8) ^ rx));
          s16x8 pv = *(const s16x8*)(p2r + u * 8);
#pragma unroll
          for (int j = 0; j < 8; ++j){
            float v = bf2f(tv[j]) + bf2f(pv[j]) + p1c[u * 8 + j];
            acc[u * 8 + j] += fmaxf(v, 0.f);
          }
        }
      } else {
#pragma unroll
        for (int u = 0; u < 4; ++u){
          s16x8 tv = *(const s16x8*)(trow + ((c0 + u * 8) ^ rx));
#pragma unroll
          for (int j = 0; j < 8; ++j){
            float v = bf2f(tv[j]) + p1c[u * 8 + j];
            acc[u * 8 + j] += fmaxf(v, 0.f);
          }
        }
      }
    }
    __syncthreads();                         // T reads done before overwrite
  }

  // write S rows (bf16)
#pragma unroll
  for (int u = 0; u < 4; ++u){
    s16x8 o;
#pragma unroll
    for (int j = 0; j < 8; ++j) o[j] = f2bf(acc[u * 8 + j]);
    *(s16x8*)(S + (size_t)(node0 * 2 + sr) * 512 + c0 + u * 8) = o;
  }
}

// ===========================================================================
// node_update v2: block = 64 rows, 512 threads (8 waves = 2 row x 4 col),
// 256 blocks (halves weight L2 traffic vs RB=32). LDS only Ms/Xs (64 KB) ->
// 2 blocks/CU = 16 waves/CU. S A-frags read direct from global (L2/L3-hot).
// Phases as before: A (m update), B+C (Gr,Gz), e1, D (Gw), e2, E (P) / readout.
// ===========================================================================
template<int PH>
__global__ __launch_bounds__(512, 4)
void node_update(const short* __restrict__ S, short* __restrict__ Pout,
                 float* __restrict__ m, float* __restrict__ h,
                 float* __restrict__ g,
                 const short* __restrict__ BtW2, const short* __restrict__ BtRZ,
                 const short* __restrict__ BtHW, const short* __restrict__ BtP,
                 const int* __restrict__ deg, const float* __restrict__ b2,
                 const float* __restrict__ br, const float* __restrict__ bz,
                 const float* __restrict__ bh)
{
  __shared__ __align__(16) char lds[65536];
  short* Ms = (short*)lds;              // [64][256] bf16 swizzled
  short* Xs = (short*)(lds + 32768);    // [64][256] bf16 swizzled
  float* Hf = (float*)lds;              // [64][256] f32 overlay (PH2 only)

  const int tid = threadIdx.x;
  const int w = tid >> 6, l = tid & 63;
  const int lr = l & 15, lg = l >> 4;
  const int wrow = w >> 2, wcol = w & 3;
  const int rb = wrow * 32;
  const int grow0 = blockIdx.x * 64;

  auto rd256 = [&](int row, int c){ return row * 256 + (c ^ ((row & 7) << 3)); };

  // ---- h into regs, acc init = m + deg*b2; Xs <- bf16(h) ----
  f32x4 hv[2][4], acc[2][4];
#pragma unroll
  for (int i = 0; i < 2; ++i)
#pragma unroll
    for (int j = 0; j < 4; ++j)
#pragma unroll
      for (int r = 0; r < 4; ++r){
        int rl = rb + i*16 + lg*4 + r, colp = wcol*64 + j*16 + lr;
        size_t gi = (size_t)(grow0 + rl) * 256 + colp;
        float base = (float)deg[(grow0 + rl) >> 1] * b2[colp];
        if (PH > 0){ base += m[gi]; hv[i][j][r] = h[gi]; }
        else hv[i][j][r] = 0.f;
        acc[i][j][r] = base;
      }
  if (PH > 0){
#pragma unroll
    for (int i = 0; i < 2; ++i)
#pragma unroll
      for (int j = 0; j < 4; ++j)
#pragma unroll
        for (int r = 0; r < 4; ++r){
          int rl = rb + i*16 + lg*4 + r, colp = wcol*64 + j*16 + lr;
          Xs[rd256(rl, colp)] = f2bf(hv[i][j][r]);
        }
  }

  // ---- Phase A: acc += S @ W2 (K=512), A-frags direct from global ----
#pragma unroll 4
  for (int c = 0; c < 16; ++c){
    s16x8 a0 = *(const s16x8*)(S + (size_t)(grow0 + rb + lr)      * 512 + c*32 + lg*8);
    s16x8 a1 = *(const s16x8*)(S + (size_t)(grow0 + rb + 16 + lr) * 512 + c*32 + lg*8);
#pragma unroll
    for (int j = 0; j < 4; ++j){
      s16x8 bb = *(const s16x8*)(BtW2 + (size_t)(wcol*64 + j*16 + lr) * 512 + c*32 + lg*8);
      acc[0][j] = MFMA16(a0, bb, acc[0][j]);
      acc[1][j] = MFMA16(a1, bb, acc[1][j]);
    }
  }
#pragma unroll
  for (int i = 0; i < 2; ++i)
#pragma unroll
    for (int j = 0; j < 4; ++j)
#pragma unroll
      for (int r = 0; r < 4; ++r){
        int rl = rb + i*16 + lg*4 + r, colp = wcol*64 + j*16 + lr;
        float v = acc[i][j][r];
        if (PH < 2) m[(size_t)(grow0 + rl) * 256 + colp] = v;
        Ms[rd256(rl, colp)] = f2bf(v);
      }
  __syncthreads();                         // Ms(m_bf) + Xs(hb) visible

  // ---- Phase B+C: Gr, Gz in one A-pass ----
  f32x4 Gr[2][4], Gz[2][4];
#pragma unroll
  for (int i = 0; i < 2; ++i)
#pragma unroll
    for (int j = 0; j < 4; ++j){ Gr[i][j] = (f32x4){0.f,0.f,0.f,0.f}; Gz[i][j] = (f32x4){0.f,0.f,0.f,0.f}; }

  auto gemmRZ = [&](const short* Ab, int koff){
#pragma unroll 2
    for (int c = 0; c < 8; ++c){
      s16x8 a0 = *(const s16x8*)(Ab + rd256(rb + lr,      c*32 + lg*8));
      s16x8 a1 = *(const s16x8*)(Ab + rd256(rb + 16 + lr, c*32 + lg*8));
#pragma unroll
      for (int j = 0; j < 4; ++j){
        int colr = wcol*64 + j*16 + lr;
        s16x8 b_r = *(const s16x8*)(BtRZ + (size_t)colr         * 512 + koff + c*32 + lg*8);
        s16x8 b_z = *(const s16x8*)(BtRZ + (size_t)(256 + colr) * 512 + koff + c*32 + lg*8);
        Gr[0][j] = MFMA16(a0, b_r, Gr[0][j]);
        Gr[1][j] = MFMA16(a1, b_r, Gr[1][j]);
        Gz[0][j] = MFMA16(a0, b_z, Gz[0][j]);
        Gz[1][j] = MFMA16(a1, b_z, Gz[1][j]);
      }
    }
  };
  gemmRZ(Ms, 0);
  if (PH > 0) gemmRZ(Xs, 256);

  // ---- e1: r, z; Xs <- bf16(r*h) ----
  f32x4 zz[2][4];
#pragma unroll
  for (int i = 0; i < 2; ++i)
#pragma unroll
    for (int j = 0; j < 4; ++j)
#pragma unroll
      for (int r = 0; r < 4; ++r){
        int colp = wcol*64 + j*16 + lr;
        zz[i][j][r] = 1.f / (1.f + __expf(-(Gz[i][j][r] + bz[colp])));
      }
  if (PH > 0){
    __syncthreads();                       // B/C's Xs(hb) reads done
#pragma unroll
    for (int i = 0; i < 2; ++i)
#pragma unroll
      for (int j = 0; j < 4; ++j)
#pragma unroll
        for (int r = 0; r < 4; ++r){
          int rl = rb + i*16 + lg*4 + r, colp = wcol*64 + j*16 + lr;
          float rr = 1.f / (1.f + __expf(-(Gr[i][j][r] + br[colp])));
          Xs[rd256(rl, colp)] = f2bf(rr * hv[i][j][r]);
        }
    __syncthreads();                       // Xs(rh) visible
  }

  // ---- Phase D: Gw = [m|rh] @ BtHW ----
  f32x4 Gw[2][4];
#pragma unroll
  for (int i = 0; i < 2; ++i)
#pragma unroll
    for (int j = 0; j < 4; ++j) Gw[i][j] = (f32x4){0.f,0.f,0.f,0.f};
  auto gemmHW = [&](const short* Ab, int koff){
#pragma unroll 2
    for (int c = 0; c < 8; ++c){
      s16x8 a0 = *(const s16x8*)(Ab + rd256(rb + lr,      c*32 + lg*8));
      s16x8 a1 = *(const s16x8*)(Ab + rd256(rb + 16 + lr, c*32 + lg*8));
#pragma unroll
      for (int j = 0; j < 4; ++j){
        s16x8 bb = *(const s16x8*)(BtHW + (size_t)(wcol*64 + j*16 + lr) * 512 + koff + c*32 + lg*8);
        Gw[0][j] = MFMA16(a0, bb, Gw[0][j]);
        Gw[1][j] = MFMA16(a1, bb, Gw[1][j]);
      }
    }
  };
  gemmHW(Ms, 0);
  if (PH > 0) gemmHW(Xs, 256);
  __syncthreads();                         // D's Ms/Xs reads done

  // ---- e2: h' ----
#pragma unroll
  for (int i = 0; i < 2; ++i)
#pragma unroll
    for (int j = 0; j < 4; ++j)
#pragma unroll
      for (int r = 0; r < 4; ++r){
        int rl = rb + i*16 + lg*4 + r, colp = wcol*64 + j*16 + lr;
        float ht = tanhf(Gw[i][j][r] + bh[colp]);
        float z  = zz[i][j][r];
        float hn = (1.f - z) * hv[i][j][r] + z * ht;
        if (PH < 2){
          h[(size_t)(grow0 + rl) * 256 + colp] = hn;
          Ms[rd256(rl, colp)] = f2bf(hn);
        } else {
          Hf[rl * 256 + colp] = hn;
        }
      }
  __syncthreads();                         // Ms(h') / Hf visible

  if (PH < 2){
    // ---- Phase E: P = h' @ BtP, 4 panels of 256 cols ----
    for (int pn = 0; pn < 4; ++pn){
      f32x4 pa0[4], pa1[4];
#pragma unroll
      for (int j = 0; j < 4; ++j){ pa0[j] = (f32x4){0.f,0.f,0.f,0.f}; pa1[j] = (f32x4){0.f,0.f,0.f,0.f}; }
#pragma unroll 2
      for (int c = 0; c < 8; ++c){
        s16x8 a0 = *(const s16x8*)(Ms + rd256(rb + lr,      c*32 + lg*8));
        s16x8 a1 = *(const s16x8*)(Ms + rd256(rb + 16 + lr, c*32 + lg*8));
#pragma unroll
        for (int j = 0; j < 4; ++j){
          s16x8 bb = *(const s16x8*)(BtP + (size_t)(pn*256 + wcol*64 + j*16 + lr) * 256 + c*32 + lg*8);
          pa0[j] = MFMA16(a0, bb, pa0[j]);
          pa1[j] = MFMA16(a1, bb, pa1[j]);
        }
      }
#pragma unroll
      for (int j = 0; j < 4; ++j)
#pragma unroll
        for (int r = 0; r < 4; ++r){
          int colp = wcol*64 + j*16 + lr;
          Pout[(size_t)(grow0 + rb + lg*4 + r)      * 1024 + pn*256 + colp] = f2bf(pa0[j][r]);
          Pout[(size_t)(grow0 + rb + 16 + lg*4 + r) * 1024 + pn*256 + colp] = f2bf(pa1[j][r]);
        }
    }
  } else {
    // ---- readout partial over the block's 64 rows ----
    int col = tid & 255, pb = tid >> 8;    // pb = batch parity
    float s = 0.f;
#pragma unroll
    for (int rr = 0; rr < 32; ++rr)
      s += Hf[(2*rr + pb) * 256 + col];
    atomicAdd(&g[pb * 256 + col], s);
  }
}

// --------------------------- ef -> bf16 conversion -------------------------
__global__ __launch_bounds__(256)
void cvt_ef(const float* __restrict__ ef, short* __restrict__ ebf){
  size_t i = (size_t)(blockIdx.x * 256 + threadIdx.x) * 8;
  f32x4 f0 = *(const f32x4*)(ef + i);
  f32x4 f1 = *(const f32x4*)(ef + i + 4);
  s16x8 o;
  o[0]=f2bf(f0[0]); o[1]=f2bf(f0[1]); o[2]=f2bf(f0[2]); o[3]=f2bf(f0[3]);
  o[4]=f2bf(f1[0]); o[5]=f2bf(f1[1]); o[6]=f2bf(f1[2]); o[7]=f2bf(f1[3]);
  *(s16x8*)(ebf + i) = o;
}

// ------------------------------- CSR build ---------------------------------
__global__ void count_kernel(const int* __restrict__ edst, int* __restrict__ counts){
  int e = blockIdx.x * 256 + threadIdx.x;
  if (e < E_EDGES) atomicAdd(&counts[edst[e]], 1);
}
__global__ void scan_kernel(const int* __restrict__ counts, int* __restrict__ row_start,
                            int* __restrict__ cursor){
  __shared__ int sums[1024];
  int t = threadIdx.x;
  int base = t * 8;
  int loc[8]; int s = 0;
#pragma unroll
  for (int i = 0; i < 8; ++i){ loc[i] = s; s += counts[base + i]; }
  sums[t] = s;
  __syncthreads();
  for (int o = 1; o < 1024; o <<= 1){
    int v = sums[t];
    int u = (t >= o) ? sums[t - o] : 0;
    __syncthreads();
    sums[t] = v + u;
    __syncthreads();
  }
  int excl = (t == 0) ? 0 : sums[t - 1];
#pragma unroll
  for (int i = 0; i < 8; ++i){ int v = excl + loc[i]; row_start[base + i] = v; cursor[base + i] = v; }
  if (t == 1023) row_start[NNODES] = sums[1023];
}
__global__ void fill_kernel(const int* __restrict__ edst, const int* __restrict__ esrc,
                            int* __restrict__ cursor, int* __restrict__ csr_eid,
                            int* __restrict__ csr_src){
  int e = blockIdx.x * 256 + threadIdx.x;
  if (e < E_EDGES){
    int pos = atomicAdd(&cursor[edst[e]], 1);
    csr_eid[pos] = e;
    csr_src[pos] = esrc[e];
  }
}

// --------------------------- weight repacking ------------------------------
// BtP [1024][256], BtE [512][64] PRE-SWIZZLED (unit ^= row&7), BtW2 [256][512],
// BtRZ [512][512] (cols r|z, K = W|U), BtHW [256][512] (K = Wh|Uh)
__global__ void prep_weights(const float* __restrict__ W1, const float* __restrict__ W2,
                             const float* __restrict__ Wr, const float* __restrict__ Ur,
                             const float* __restrict__ Wz, const float* __restrict__ Uz,
                             const float* __restrict__ Wh, const float* __restrict__ Uh,
                             short* __restrict__ BtP, short* __restrict__ BtE,
                             short* __restrict__ BtW2, short* __restrict__ BtRZ,
                             short* __restrict__ BtHW)
{
  int id = blockIdx.x * 256 + threadIdx.x;
  if (id < 262144){                       // BtP
    int jj = id >> 8, k = id & 255;
    float v = (jj < 512) ? W1[(size_t)k * 512 + jj] : W1[(size_t)(256 + k) * 512 + (jj - 512)];
    BtP[id] = f2bf(v);
  } else if (id < 294912){                // BtE (swizzled store)
    int i2 = id - 262144; int jj = i2 >> 6, c = i2 & 63;
    BtE[jj * 64 + (c ^ ((jj & 7) << 3))] = f2bf(W1[(size_t)(512 + c) * 512 + jj]);
  } else if (id < 425984){                // BtW2
    int i2 = id - 294912; int n = i2 >> 9, k = i2 & 511;
    BtW2[i2] = f2bf(W2[(size_t)k * 256 + n]);
  } else if (id < 688128){                // BtRZ
    int i2 = id - 425984; int col = i2 >> 9, k = i2 & 511;
    float v;
    if (col < 256) v = (k < 256) ? Wr[(size_t)k * 256 + col] : Ur[(size_t)(k - 256) * 256 + col];
    else { int c2 = col - 256; v = (k < 256) ? Wz[(size_t)k * 256 + c2] : Uz[(size_t)(k - 256) * 256 + c2]; }
    BtRZ[i2] = f2bf(v);
  } else if (id < 819200){                // BtHW
    int i2 = id - 688128; int col = i2 >> 9, k = i2 & 511;
    float v = (k < 256) ? Wh[(size_t)k * 256 + col] : Uh[(size_t)(k - 256) * 256 + col];
    BtHW[i2] = f2bf(v);
  }
}

// -------------------------------- readout ----------------------------------
__global__ __launch_bounds__(256)
void readout2(const float* __restrict__ g, const float* __restrict__ Wo,
              const float* __restrict__ bo, float* __restrict__ out){
  int t = threadIdx.x;
  int b = t >> 7, o = t & 127;
  float s = bo[o];
  for (int c = 0; c < 256; ++c) s += g[b * 256 + c] * Wo[c * 128 + o];
  out[b * 128 + o] = s;
}

// ===========================================================================
extern "C" void kernel_launch(void* const* d_in, const int* in_sizes, int n_in,
                              void* d_out, int out_size, void* d_ws, size_t ws_size,
                              hipStream_t stream)
{
  const float* ef  = (const float*)d_in[0];
  const float* W1  = (const float*)d_in[1];
  const float* b1  = (const float*)d_in[2];
  const float* W2  = (const float*)d_in[3];
  const float* b2  = (const float*)d_in[4];
  const float* Wr  = (const float*)d_in[5];
  const float* Ur  = (const float*)d_in[6];
  const float* br  = (const float*)d_in[7];
  const float* Wz  = (const float*)d_in[8];
  const float* Uz  = (const float*)d_in[9];
  const float* bz  = (const float*)d_in[10];
  const float* Wh  = (const float*)d_in[11];
  const float* Uh  = (const float*)d_in[12];
  const float* bh  = (const float*)d_in[13];
  const float* Wo  = (const float*)d_in[14];
  const float* bo  = (const float*)d_in[15];
  const int* esrc  = (const int*)d_in[16];
  const int* edst  = (const int*)d_in[17];

  char* base = (char*)d_ws;
  size_t off = 0;
  auto alloc = [&](size_t bytes) -> char* {
    off = (off + 255) & ~(size_t)255;
    char* p = base + off;
    off += bytes;
    return p;
  };
  float* h    = (float*)alloc((size_t)NB * 256 * 4);   // 16 MB
  float* m    = (float*)alloc((size_t)NB * 256 * 4);   // 16 MB
  short* P    = (short*)alloc((size_t)NB * 1024 * 2);  // 32 MB
  short* S    = (short*)alloc((size_t)NB * 512 * 2);   // 16 MB
  short* ebf  = (short*)alloc((size_t)E_EDGES * 2 * EDIM * 2);  // 33.5 MB
  short* BtP  = (short*)alloc(262144 * 2);
  short* BtE  = (short*)alloc(32768 * 2);
  short* BtW2 = (short*)alloc(131072 * 2);
  short* BtRZ = (short*)alloc(262144 * 2);
  short* BtHW = (short*)alloc(131072 * 2);
  int* counts = (int*)alloc(NNODES * 4);
  int* rs     = (int*)alloc((NNODES + 1) * 4);
  int* cursor = (int*)alloc(NNODES * 4);
  int* ceid   = (int*)alloc(E_EDGES * 4);
  int* csrc   = (int*)alloc(E_EDGES * 4);
  float* g    = (float*)alloc(512 * 4);
  // total ~120 MB << 256 MiB workspace (no E1 buffer anymore)

  dim3 blk(256);

  // ------------------------------- prep ----------------------------------
  hipMemsetAsync(g,  0, 512 * 4, stream);
  hipMemsetAsync(counts, 0, NNODES * 4, stream);
  prep_weights<<<3200, blk, 0, stream>>>(W1, W2, Wr, Ur, Wz, Uz, Wh, Uh,
                                         BtP, BtE, BtW2, BtRZ, BtHW);
  cvt_ef<<<(E_EDGES * 2 * EDIM) / (256 * 8), blk, 0, stream>>>(ef, ebf);
  count_kernel<<<512, blk, 0, stream>>>(edst, counts);
  scan_kernel<<<1, 1024, 0, stream>>>(counts, rs, cursor);
  fill_kernel<<<512, blk, 0, stream>>>(edst, esrc, cursor, ceid, csrc);

  // ----------------------------- iterations ------------------------------
  edge_fused<false><<<NNODES / 16, dim3(512), 0, stream>>>(
      ebf, BtE, P, ceid, csrc, rs, b1, S);
  node_update<0><<<NB / 64, dim3(512), 0, stream>>>(S, P, m, h, g,
      BtW2, BtRZ, BtHW, BtP, counts, b2, br, bz, bh);

  edge_fused<true><<<NNODES / 16, dim3(512), 0, stream>>>(
      ebf, BtE, P, ceid, csrc, rs, b1, S);
  node_update<1><<<NB / 64, dim3(512), 0, stream>>>(S, P, m, h, g,
      BtW2, BtRZ, BtHW, BtP, counts, b2, br, bz, bh);

  edge_fused<true><<<NNODES / 16, dim3(512), 0, stream>>>(
      ebf, BtE, P, ceid, csrc, rs, b1, S);
  node_update<2><<<NB / 64, dim3(512), 0, stream>>>(S, P, m, h, g,
      BtW2, BtRZ, BtHW, BtP, counts, b2, br, bz, bh);

  // ------------------------------ readout --------------------------------
  readout2<<<1, blk, 0, stream>>>(g, Wo, bo, (float*)d_out);
}

// Round 7
// 1025.603 us; speedup vs baseline: 1.1210x; 1.1210x over previous
//
#include <hip/hip_runtime.h>
#include <hip/hip_bf16.h>

#define E_EDGES 131072
#define NNODES  8192
#define NB      16384   // N_NODES * BATCH rows
#define HID     256
#define EDIM    64
#define MLPH    512
#define OUTD    128
#define NIT     3

typedef short s16x4 __attribute__((ext_vector_type(4)));
typedef short s16x8 __attribute__((ext_vector_type(8)));
typedef float f32x4 __attribute__((ext_vector_type(4)));

__device__ __forceinline__ short f2bf(float f){
  unsigned int x = __builtin_bit_cast(unsigned int, f);
  x += 0x7fffu + ((x >> 16) & 1u);          // RNE
  return (short)(x >> 16);
}
__device__ __forceinline__ float bf2f(short s){
  unsigned int x = ((unsigned int)(unsigned short)s) << 16;
  return __builtin_bit_cast(float, x);
}
#define MFMA16(a,b,c) __builtin_amdgcn_mfma_f32_16x16x32_bf16((a),(b),(c),0,0,0)

// ===========================================================================
// edge_fused v2: block = 16 nodes (32 S-rows), 512 threads, E1 never in HBM.
// Window = 64 edge-rows (32 CSR positions) per barrier pair (16 barriers/blk).
//  stage (prev epoch): Esh[32]=ceid window, Csh[2][32]=csrc window (dbuf)
//  MFMA: per wave, 4 m-frags x 4 n-frags (B = reg-resident BtE slice, 64 cols)
//        -> T[64][512] bf16 (row-XOR-swizzled)
//  accum: thread owns (sr=tid>>4 S-row, c0=(tid&15)*32 cols); for its node's
//        edges in window: acc += relu(T[er] + P1+P2(+b1))  [P terms if USE_P]
//  All loads 1-deep: eid/src from LDS, only P2/ebf go to global (L2/L3-hot).
// ===========================================================================
template<bool USE_P>
__global__ __launch_bounds__(512, 2)
void edge_fused(const short* __restrict__ ebf, const short* __restrict__ BtE,
                const short* __restrict__ P, const int* __restrict__ ceid,
                const int* __restrict__ csrc, const int* __restrict__ rs,
                const float* __restrict__ b1, short* __restrict__ S)
{
  __shared__ __align__(16) short T[64 * 512];   // 64 KB
  __shared__ int Esh[32];
  __shared__ int Csh[2][32];

  const int tid = threadIdx.x;
  const int w  = tid >> 6, l = tid & 63;
  const int lr = l & 15, lg = l >> 4;
  const int node0 = blockIdx.x * 16;
  const int p0 = rs[node0], p1 = rs[node0 + 16];

  // ---- B-operand: this wave's 64-col BtE slice in registers ----
  s16x8 Bf0[4], Bf1[4];
#pragma unroll
  for (int nf = 0; nf < 4; ++nf){
    const short* bp = BtE + (size_t)(w * 64 + nf * 16 + lr) * 64 + lg * 8;
    Bf0[nf] = *(const s16x8*)bp;
    Bf1[nf] = *(const s16x8*)(bp + 32);
  }

  // ---- accum ownership ----
  const int sr = tid >> 4;                 // 0..31 S-row within block
  const int nd = node0 + (sr >> 1);
  const int sb = sr & 1;
  const int c0 = (tid & 15) * 32;
  const int ps = rs[nd], pe = rs[nd + 1];

  float acc[32], p1c[32];
#pragma unroll
  for (int c = 0; c < 32; ++c) acc[c] = 0.f;
#pragma unroll
  for (int c = 0; c < 32; ++c) p1c[c] = b1[c0 + c];
  if (USE_P){
#pragma unroll
    for (int u = 0; u < 4; ++u){
      s16x8 pv = *(const s16x8*)(P + (size_t)(nd * 2 + sb) * 1024 + c0 + u * 8);
#pragma unroll
      for (int j = 0; j < 8; ++j) p1c[u * 8 + j] += bf2f(pv[j]);
    }
  }

  const int nwin = (p1 - p0 + 31) >> 5;

  for (int t = 0; t < nwin; ++t){
    const int pw0 = p0 + t * 32;
    const int cb = t & 1;
    // ---- stage window indices (epoch shared with previous accum) ----
    if (tid < 32){
      int p = pw0 + tid; if (p > E_EDGES - 1) p = E_EDGES - 1;
      Esh[tid] = ceid[p];
    } else if (tid < 64){
      int p = pw0 + tid - 32; if (p > E_EDGES - 1) p = E_EDGES - 1;
      Csh[cb][tid - 32] = csrc[p];
    }
    __syncthreads();                       // Esh/Csh ready; prev T-reads done

    // ---- MFMA phase: issue all A-gathers first, then 32 MFMAs ----
    int eidv[4];
#pragma unroll
    for (int mf = 0; mf < 4; ++mf) eidv[mf] = Esh[mf * 8 + (lr >> 1)];
    s16x8 A0[4], A1[4];
#pragma unroll
    for (int mf = 0; mf < 4; ++mf){
      const short* ap = ebf + ((size_t)eidv[mf] * 2 + (lr & 1)) * 64 + lg * 8;
      A0[mf] = *(const s16x8*)ap;
      A1[mf] = *(const s16x8*)(ap + 32);
    }
#pragma unroll
    for (int mf = 0; mf < 4; ++mf){
      f32x4 cf[4];
#pragma unroll
      for (int nf = 0; nf < 4; ++nf){
        cf[nf] = (f32x4){0.f,0.f,0.f,0.f};
        cf[nf] = MFMA16(A0[mf], Bf0[nf], cf[nf]);
        cf[nf] = MFMA16(A1[mf], Bf1[nf], cf[nf]);
      }
#pragma unroll
      for (int nf = 0; nf < 4; ++nf){
        int col = w * 64 + nf * 16 + lr;
#pragma unroll
        for (int r = 0; r < 4; ++r){
          int row = mf * 16 + lg * 4 + r;
          T[row * 512 + (col ^ ((row & 7) << 3))] = f2bf(cf[nf][r]);
        }
      }
    }
    __syncthreads();                       // T visible

    // ---- accum: this thread's node-edges within the window ----
    int pa = ps > pw0 ? ps : pw0;
    int pb = pe < pw0 + 32 ? pe : pw0 + 32;
    for (int p = pa; p < pb; ++p){
      int er = (p - pw0) * 2 + sb;
      int rx = (er & 7) << 3;
      const short* trow = T + er * 512;
      if (USE_P){
        const short* p2r = P + ((size_t)Csh[cb][p - pw0] * 2 + sb) * 1024 + 512 + c0;
#pragma unroll
        for (int u = 0; u < 4; ++u){
          s16x8 tv = *(const s16x8*)(trow + ((c0 + u * 8) ^ rx));
          s16x8 pv = *(const s16x8*)(p2r + u * 8);
#pragma unroll
          for (int j = 0; j < 8; ++j){
            float v = bf2f(tv[j]) + bf2f(pv[j]) + p1c[u * 8 + j];
            acc[u * 8 + j] += fmaxf(v, 0.f);
          }
        }
      } else {
#pragma unroll
        for (int u = 0; u < 4; ++u){
          s16x8 tv = *(const s16x8*)(trow + ((c0 + u * 8) ^ rx));
#pragma unroll
          for (int j = 0; j < 8; ++j){
            float v = bf2f(tv[j]) + p1c[u * 8 + j];
            acc[u * 8 + j] += fmaxf(v, 0.f);
          }
        }
      }
    }
  }

  // ---- write S rows (bf16); deg-0 nodes naturally write zeros ----
#pragma unroll
  for (int u = 0; u < 4; ++u){
    s16x8 o;
#pragma unroll
    for (int j = 0; j < 8; ++j) o[j] = f2bf(acc[u * 8 + j]);
    *(s16x8*)(S + (size_t)(node0 * 2 + sr) * 512 + c0 + u * 8) = o;
  }
}

// ===========================================================================
// node_update: block = 64 rows, 512 threads (8 waves = 2 row x 4 col),
// 256 blocks. LDS Ms/Xs (64 KB). S A-frags direct from global (L2/L3-hot).
// Phases: A (m update), B+C (Gr,Gz), e1, D (Gw), e2, E (P) / readout.
// ===========================================================================
template<int PH>
__global__ __launch_bounds__(512, 2)
void node_update(const short* __restrict__ S, short* __restrict__ Pout,
                 float* __restrict__ m, float* __restrict__ h,
                 float* __restrict__ g,
                 const short* __restrict__ BtW2, const short* __restrict__ BtRZ,
                 const short* __restrict__ BtHW, const short* __restrict__ BtP,
                 const int* __restrict__ deg, const float* __restrict__ b2,
                 const float* __restrict__ br, const float* __restrict__ bz,
                 const float* __restrict__ bh)
{
  __shared__ __align__(16) char lds[65536];
  short* Ms = (short*)lds;              // [64][256] bf16 swizzled
  short* Xs = (short*)(lds + 32768);    // [64][256] bf16 swizzled
  float* Hf = (float*)lds;              // [64][256] f32 overlay (PH2 only)

  const int tid = threadIdx.x;
  const int w = tid >> 6, l = tid & 63;
  const int lr = l & 15, lg = l >> 4;
  const int wrow = w >> 2, wcol = w & 3;
  const int rb = wrow * 32;
  const int grow0 = blockIdx.x * 64;

  auto rd256 = [&](int row, int c){ return row * 256 + (c ^ ((row & 7) << 3)); };

  // ---- h into regs, acc init = m + deg*b2; Xs <- bf16(h) ----
  f32x4 hv[2][4], acc[2][4];
#pragma unroll
  for (int i = 0; i < 2; ++i)
#pragma unroll
    for (int j = 0; j < 4; ++j)
#pragma unroll
      for (int r = 0; r < 4; ++r){
        int rl = rb + i*16 + lg*4 + r, colp = wcol*64 + j*16 + lr;
        size_t gi = (size_t)(grow0 + rl) * 256 + colp;
        float base = (float)deg[(grow0 + rl) >> 1] * b2[colp];
        if (PH > 0){ base += m[gi]; hv[i][j][r] = h[gi]; }
        else hv[i][j][r] = 0.f;
        acc[i][j][r] = base;
      }
  if (PH > 0){
#pragma unroll
    for (int i = 0; i < 2; ++i)
#pragma unroll
      for (int j = 0; j < 4; ++j)
#pragma unroll
        for (int r = 0; r < 4; ++r){
          int rl = rb + i*16 + lg*4 + r, colp = wcol*64 + j*16 + lr;
          Xs[rd256(rl, colp)] = f2bf(hv[i][j][r]);
        }
  }

  // ---- Phase A: acc += S @ W2 (K=512), A-frags direct from global ----
#pragma unroll 4
  for (int c = 0; c < 16; ++c){
    s16x8 a0 = *(const s16x8*)(S + (size_t)(grow0 + rb + lr)      * 512 + c*32 + lg*8);
    s16x8 a1 = *(const s16x8*)(S + (size_t)(grow0 + rb + 16 + lr) * 512 + c*32 + lg*8);
#pragma unroll
    for (int j = 0; j < 4; ++j){
      s16x8 bb = *(const s16x8*)(BtW2 + (size_t)(wcol*64 + j*16 + lr) * 512 + c*32 + lg*8);
      acc[0][j] = MFMA16(a0, bb, acc[0][j]);
      acc[1][j] = MFMA16(a1, bb, acc[1][j]);
    }
  }
#pragma unroll
  for (int i = 0; i < 2; ++i)
#pragma unroll
    for (int j = 0; j < 4; ++j)
#pragma unroll
      for (int r = 0; r < 4; ++r){
        int rl = rb + i*16 + lg*4 + r, colp = wcol*64 + j*16 + lr;
        float v = acc[i][j][r];
        if (PH < 2) m[(size_t)(grow0 + rl) * 256 + colp] = v;
        Ms[rd256(rl, colp)] = f2bf(v);
      }
  __syncthreads();                         // Ms(m_bf) + Xs(hb) visible

  // ---- Phase B+C: Gr, Gz in one A-pass ----
  f32x4 Gr[2][4], Gz[2][4];
#pragma unroll
  for (int i = 0; i < 2; ++i)
#pragma unroll
    for (int j = 0; j < 4; ++j){ Gr[i][j] = (f32x4){0.f,0.f,0.f,0.f}; Gz[i][j] = (f32x4){0.f,0.f,0.f,0.f}; }

  auto gemmRZ = [&](const short* Ab, int koff){
#pragma unroll 2
    for (int c = 0; c < 8; ++c){
      s16x8 a0 = *(const s16x8*)(Ab + rd256(rb + lr,      c*32 + lg*8));
      s16x8 a1 = *(const s16x8*)(Ab + rd256(rb + 16 + lr, c*32 + lg*8));
#pragma unroll
      for (int j = 0; j < 4; ++j){
        int colr = wcol*64 + j*16 + lr;
        s16x8 b_r = *(const s16x8*)(BtRZ + (size_t)colr         * 512 + koff + c*32 + lg*8);
        s16x8 b_z = *(const s16x8*)(BtRZ + (size_t)(256 + colr) * 512 + koff + c*32 + lg*8);
        Gr[0][j] = MFMA16(a0, b_r, Gr[0][j]);
        Gr[1][j] = MFMA16(a1, b_r, Gr[1][j]);
        Gz[0][j] = MFMA16(a0, b_z, Gz[0][j]);
        Gz[1][j] = MFMA16(a1, b_z, Gz[1][j]);
      }
    }
  };
  gemmRZ(Ms, 0);
  if (PH > 0) gemmRZ(Xs, 256);

  // ---- e1: r, z; Xs <- bf16(r*h) ----
  f32x4 zz[2][4];
#pragma unroll
  for (int i = 0; i < 2; ++i)
#pragma unroll
    for (int j = 0; j < 4; ++j)
#pragma unroll
      for (int r = 0; r < 4; ++r){
        int colp = wcol*64 + j*16 + lr;
        zz[i][j][r] = 1.f / (1.f + __expf(-(Gz[i][j][r] + bz[colp])));
      }
  if (PH > 0){
    __syncthreads();                       // B/C's Xs(hb) reads done
#pragma unroll
    for (int i = 0; i < 2; ++i)
#pragma unroll
      for (int j = 0; j < 4; ++j)
#pragma unroll
        for (int r = 0; r < 4; ++r){
          int rl = rb + i*16 + lg*4 + r, colp = wcol*64 + j*16 + lr;
          float rr = 1.f / (1.f + __expf(-(Gr[i][j][r] + br[colp])));
          Xs[rd256(rl, colp)] = f2bf(rr * hv[i][j][r]);
        }
    __syncthreads();                       // Xs(rh) visible
  }

  // ---- Phase D: Gw = [m|rh] @ BtHW ----
  f32x4 Gw[2][4];
#pragma unroll
  for (int i = 0; i < 2; ++i)
#pragma unroll
    for (int j = 0; j < 4; ++j) Gw[i][j] = (f32x4){0.f,0.f,0.f,0.f};
  auto gemmHW = [&](const short* Ab, int koff){
#pragma unroll 2
    for (int c = 0; c < 8; ++c){
      s16x8 a0 = *(const s16x8*)(Ab + rd256(rb + lr,      c*32 + lg*8));
      s16x8 a1 = *(const s16x8*)(Ab + rd256(rb + 16 + lr, c*32 + lg*8));
#pragma unroll
      for (int j = 0; j < 4; ++j){
        s16x8 bb = *(const s16x8*)(BtHW + (size_t)(wcol*64 + j*16 + lr) * 512 + koff + c*32 + lg*8);
        Gw[0][j] = MFMA16(a0, bb, Gw[0][j]);
        Gw[1][j] = MFMA16(a1, bb, Gw[1][j]);
      }
    }
  };
  gemmHW(Ms, 0);
  if (PH > 0) gemmHW(Xs, 256);
  __syncthreads();                         // D's Ms/Xs reads done

  // ---- e2: h' ----
#pragma unroll
  for (int i = 0; i < 2; ++i)
#pragma unroll
    for (int j = 0; j < 4; ++j)
#pragma unroll
      for (int r = 0; r < 4; ++r){
        int rl = rb + i*16 + lg*4 + r, colp = wcol*64 + j*16 + lr;
        float ht = tanhf(Gw[i][j][r] + bh[colp]);
        float z  = zz[i][j][r];
        float hn = (1.f - z) * hv[i][j][r] + z * ht;
        if (PH < 2){
          h[(size_t)(grow0 + rl) * 256 + colp] = hn;
          Ms[rd256(rl, colp)] = f2bf(hn);
        } else {
          Hf[rl * 256 + colp] = hn;
        }
      }
  __syncthreads();                         // Ms(h') / Hf visible

  if (PH < 2){
    // ---- Phase E: P = h' @ BtP, 4 panels of 256 cols ----
    for (int pn = 0; pn < 4; ++pn){
      f32x4 pa0[4], pa1[4];
#pragma unroll
      for (int j = 0; j < 4; ++j){ pa0[j] = (f32x4){0.f,0.f,0.f,0.f}; pa1[j] = (f32x4){0.f,0.f,0.f,0.f}; }
#pragma unroll 2
      for (int c = 0; c < 8; ++c){
        s16x8 a0 = *(const s16x8*)(Ms + rd256(rb + lr,      c*32 + lg*8));
        s16x8 a1 = *(const s16x8*)(Ms + rd256(rb + 16 + lr, c*32 + lg*8));
#pragma unroll
        for (int j = 0; j < 4; ++j){
          s16x8 bb = *(const s16x8*)(BtP + (size_t)(pn*256 + wcol*64 + j*16 + lr) * 256 + c*32 + lg*8);
          pa0[j] = MFMA16(a0, bb, pa0[j]);
          pa1[j] = MFMA16(a1, bb, pa1[j]);
        }
      }
#pragma unroll
      for (int j = 0; j < 4; ++j)
#pragma unroll
        for (int r = 0; r < 4; ++r){
          int colp = wcol*64 + j*16 + lr;
          Pout[(size_t)(grow0 + rb + lg*4 + r)      * 1024 + pn*256 + colp] = f2bf(pa0[j][r]);
          Pout[(size_t)(grow0 + rb + 16 + lg*4 + r) * 1024 + pn*256 + colp] = f2bf(pa1[j][r]);
        }
    }
  } else {
    // ---- readout partial over the block's 64 rows ----
    int col = tid & 255, pb = tid >> 8;    // pb = batch parity
    float s = 0.f;
#pragma unroll
    for (int rr = 0; rr < 32; ++rr)
      s += Hf[(2*rr + pb) * 256 + col];
    atomicAdd(&g[pb * 256 + col], s);
  }
}

// --------------------------- ef -> bf16 conversion -------------------------
__global__ __launch_bounds__(256)
void cvt_ef(const float* __restrict__ ef, short* __restrict__ ebf){
  size_t i = (size_t)(blockIdx.x * 256 + threadIdx.x) * 8;
  f32x4 f0 = *(const f32x4*)(ef + i);
  f32x4 f1 = *(const f32x4*)(ef + i + 4);
  s16x8 o;
  o[0]=f2bf(f0[0]); o[1]=f2bf(f0[1]); o[2]=f2bf(f0[2]); o[3]=f2bf(f0[3]);
  o[4]=f2bf(f1[0]); o[5]=f2bf(f1[1]); o[6]=f2bf(f1[2]); o[7]=f2bf(f1[3]);
  *(s16x8*)(ebf + i) = o;
}

// ------------------------------- CSR build ---------------------------------
__global__ void count_kernel(const int* __restrict__ edst, int* __restrict__ counts){
  int e = blockIdx.x * 256 + threadIdx.x;
  if (e < E_EDGES) atomicAdd(&counts[edst[e]], 1);
}
__global__ void scan_kernel(const int* __restrict__ counts, int* __restrict__ row_start,
                            int* __restrict__ cursor){
  __shared__ int sums[1024];
  int t = threadIdx.x;
  int base = t * 8;
  int loc[8]; int s = 0;
#pragma unroll
  for (int i = 0; i < 8; ++i){ loc[i] = s; s += counts[base + i]; }
  sums[t] = s;
  __syncthreads();
  for (int o = 1; o < 1024; o <<= 1){
    int v = sums[t];
    int u = (t >= o) ? sums[t - o] : 0;
    __syncthreads();
    sums[t] = v + u;
    __syncthreads();
  }
  int excl = (t == 0) ? 0 : sums[t - 1];
#pragma unroll
  for (int i = 0; i < 8; ++i){ int v = excl + loc[i]; row_start[base + i] = v; cursor[base + i] = v; }
  if (t == 1023) row_start[NNODES] = sums[1023];
}
__global__ void fill_kernel(const int* __restrict__ edst, const int* __restrict__ esrc,
                            int* __restrict__ cursor, int* __restrict__ csr_eid,
                            int* __restrict__ csr_src){
  int e = blockIdx.x * 256 + threadIdx.x;
  if (e < E_EDGES){
    int pos = atomicAdd(&cursor[edst[e]], 1);
    csr_eid[pos] = e;
    csr_src[pos] = esrc[e];
  }
}

// --------------------------- weight repacking ------------------------------
// BtP [1024][256], BtE [512][64] (plain), BtW2 [256][512],
// BtRZ [512][512] (cols r|z, K = W|U), BtHW [256][512] (K = Wh|Uh)
__global__ void prep_weights(const float* __restrict__ W1, const float* __restrict__ W2,
                             const float* __restrict__ Wr, const float* __restrict__ Ur,
                             const float* __restrict__ Wz, const float* __restrict__ Uz,
                             const float* __restrict__ Wh, const float* __restrict__ Uh,
                             short* __restrict__ BtP, short* __restrict__ BtE,
                             short* __restrict__ BtW2, short* __restrict__ BtRZ,
                             short* __restrict__ BtHW)
{
  int id = blockIdx.x * 256 + threadIdx.x;
  if (id < 262144){                       // BtP
    int jj = id >> 8, k = id & 255;
    float v = (jj < 512) ? W1[(size_t)k * 512 + jj] : W1[(size_t)(256 + k) * 512 + (jj - 512)];
    BtP[id] = f2bf(v);
  } else if (id < 294912){                // BtE (plain [512][64])
    int i2 = id - 262144; int jj = i2 >> 6, c = i2 & 63;
    BtE[i2] = f2bf(W1[(size_t)(512 + c) * 512 + jj]);
  } else if (id < 425984){                // BtW2
    int i2 = id - 294912; int n = i2 >> 9, k = i2 & 511;
    BtW2[i2] = f2bf(W2[(size_t)k * 256 + n]);
  } else if (id < 688128){                // BtRZ
    int i2 = id - 425984; int col = i2 >> 9, k = i2 & 511;
    float v;
    if (col < 256) v = (k < 256) ? Wr[(size_t)k * 256 + col] : Ur[(size_t)(k - 256) * 256 + col];
    else { int c2 = col - 256; v = (k < 256) ? Wz[(size_t)k * 256 + c2] : Uz[(size_t)(k - 256) * 256 + c2]; }
    BtRZ[i2] = f2bf(v);
  } else if (id < 819200){                // BtHW
    int i2 = id - 688128; int col = i2 >> 9, k = i2 & 511;
    float v = (k < 256) ? Wh[(size_t)k * 256 + col] : Uh[(size_t)(k - 256) * 256 + col];
    BtHW[i2] = f2bf(v);
  }
}

// -------------------------------- readout ----------------------------------
__global__ __launch_bounds__(256)
void readout2(const float* __restrict__ g, const float* __restrict__ Wo,
              const float* __restrict__ bo, float* __restrict__ out){
  int t = threadIdx.x;
  int b = t >> 7, o = t & 127;
  float s = bo[o];
  for (int c = 0; c < 256; ++c) s += g[b * 256 + c] * Wo[c * 128 + o];
  out[b * 128 + o] = s;
}

// ===========================================================================
extern "C" void kernel_launch(void* const* d_in, const int* in_sizes, int n_in,
                              void* d_out, int out_size, void* d_ws, size_t ws_size,
                              hipStream_t stream)
{
  const float* ef  = (const float*)d_in[0];
  const float* W1  = (const float*)d_in[1];
  const float* b1  = (const float*)d_in[2];
  const float* W2  = (const float*)d_in[3];
  const float* b2  = (const float*)d_in[4];
  const float* Wr  = (const float*)d_in[5];
  const float* Ur  = (const float*)d_in[6];
  const float* br  = (const float*)d_in[7];
  const float* Wz  = (const float*)d_in[8];
  const float* Uz  = (const float*)d_in[9];
  const float* bz  = (const float*)d_in[10];
  const float* Wh  = (const float*)d_in[11];
  const float* Uh  = (const float*)d_in[12];
  const float* bh  = (const float*)d_in[13];
  const float* Wo  = (const float*)d_in[14];
  const float* bo  = (const float*)d_in[15];
  const int* esrc  = (const int*)d_in[16];
  const int* edst  = (const int*)d_in[17];

  char* base = (char*)d_ws;
  size_t off = 0;
  auto alloc = [&](size_t bytes) -> char* {
    off = (off + 255) & ~(size_t)255;
    char* p = base + off;
    off += bytes;
    return p;
  };
  float* h    = (float*)alloc((size_t)NB * 256 * 4);   // 16 MB
  float* m    = (float*)alloc((size_t)NB * 256 * 4);   // 16 MB
  short* P    = (short*)alloc((size_t)NB * 1024 * 2);  // 32 MB
  short* S    = (short*)alloc((size_t)NB * 512 * 2);   // 16 MB
  short* ebf  = (short*)alloc((size_t)E_EDGES * 2 * EDIM * 2);  // 33.5 MB
  short* BtP  = (short*)alloc(262144 * 2);
  short* BtE  = (short*)alloc(32768 * 2);
  short* BtW2 = (short*)alloc(131072 * 2);
  short* BtRZ = (short*)alloc(262144 * 2);
  short* BtHW = (short*)alloc(131072 * 2);
  int* counts = (int*)alloc(NNODES * 4);
  int* rs     = (int*)alloc((NNODES + 1) * 4);
  int* cursor = (int*)alloc(NNODES * 4);
  int* ceid   = (int*)alloc(E_EDGES * 4);
  int* csrc   = (int*)alloc(E_EDGES * 4);
  float* g    = (float*)alloc(512 * 4);
  // total ~120 MB << 256 MiB workspace

  dim3 blk(256);

  // ------------------------------- prep ----------------------------------
  hipMemsetAsync(g,  0, 512 * 4, stream);
  hipMemsetAsync(counts, 0, NNODES * 4, stream);
  prep_weights<<<3200, blk, 0, stream>>>(W1, W2, Wr, Ur, Wz, Uz, Wh, Uh,
                                         BtP, BtE, BtW2, BtRZ, BtHW);
  cvt_ef<<<(E_EDGES * 2 * EDIM) / (256 * 8), blk, 0, stream>>>(ef, ebf);
  count_kernel<<<512, blk, 0, stream>>>(edst, counts);
  scan_kernel<<<1, 1024, 0, stream>>>(counts, rs, cursor);
  fill_kernel<<<512, blk, 0, stream>>>(edst, esrc, cursor, ceid, csrc);

  // ----------------------------- iterations ------------------------------
  edge_fused<false><<<NNODES / 16, dim3(512), 0, stream>>>(
      ebf, BtE, P, ceid, csrc, rs, b1, S);
  node_update<0><<<NB / 64, dim3(512), 0, stream>>>(S, P, m, h, g,
      BtW2, BtRZ, BtHW, BtP, counts, b2, br, bz, bh);

  edge_fused<true><<<NNODES / 16, dim3(512), 0, stream>>>(
      ebf, BtE, P, ceid, csrc, rs, b1, S);
  node_update<1><<<NB / 64, dim3(512), 0, stream>>>(S, P, m, h, g,
      BtW2, BtRZ, BtHW, BtP, counts, b2, br, bz, bh);

  edge_fused<true><<<NNODES / 16, dim3(512), 0, stream>>>(
      ebf, BtE, P, ceid, csrc, rs, b1, S);
  node_update<2><<<NB / 64, dim3(512), 0, stream>>>(S, P, m, h, g,
      BtW2, BtRZ, BtHW, BtP, counts, b2, br, bz, bh);

  // ------------------------------ readout --------------------------------
  readout2<<<1, blk, 0, stream>>>(g, Wo, bo, (float*)d_out);
}